// Round 3
// baseline (78.930 us; speedup 1.0000x reference)
//
#include <hip/hip_runtime.h>
#include <stdint.h>

// GGML Q8_0 fused dequant + GEMM:  out[16][8192] = x[16][8192] . W^T + bias
// HARNESS: quantized_weight arrives as int32, one GGML byte per element
// (zero-extended): 71,303,168 elems = 285.2 MB -> HBM-bound, ~45 us floor.
//
// R3: no LDS weight staging (zero reuse -> staging was pure overhead).
// 512 blocks x 512 thr (8 waves). Block owns 16 output cols; wave w owns a
// K-eighth (32 Q8 blocks = 32 x mfma_f32_16x16x32_f16). Each lane loads its
// own 8 quants + scale as aligned dwordx2 directly from global, dequants
// in-register (perm/xor/pk_add trick), MFMA, then LDS cross-wave reduce.

typedef _Float16 half8   __attribute__((ext_vector_type(8)));
typedef _Float16 half2v  __attribute__((ext_vector_type(2)));
typedef float    float4v __attribute__((ext_vector_type(4)));
typedef uint2    __attribute__((may_alias)) u2a;
typedef float4v  __attribute__((may_alias)) f4a;

// two zero-extended quant bytes (in .b0 of lo,hi) -> packed f16 pair == exact q
// perm: [lo.b0, 0, hi.b0, 0] ; ^0x64806480 -> f16 bits 0x6400|(q+128) = 1152+q
// pk_add(-1152) -> exact integer q in f16.
__device__ __forceinline__ uint32_t qpair(uint32_t lo, uint32_t hi) {
  uint32_t r = __builtin_amdgcn_perm(hi, lo, 0x0C040C00u);
  r ^= 0x64806480u;
  half2v v = __builtin_bit_cast(half2v, r);
  v = v + __builtin_bit_cast(half2v, (uint32_t)0xE480E480u); // -1152,-1152
  return __builtin_bit_cast(uint32_t, v);
}

extern "C" __global__ __launch_bounds__(512, 4)
void q8lin_kernel(const float* __restrict__ x,
                  const int* __restrict__ wq,
                  const float* __restrict__ bias,
                  float* __restrict__ out)
{
  __shared__ __align__(16) float red[8][16][16]; // [wave][col][row], 8 KiB

  const int tid  = threadIdx.x;
  const int wv   = tid >> 6;    // K-eighth
  const int lane = tid & 63;
  const int c    = lane & 15;   // A-row (batch) and B-col (weight row)
  const int ksub = lane >> 4;   // k-subgroup within MFMA
  const int g    = blockIdx.x;  // output cols [g*16, g*16+16)

  // weight row pointer for this lane's column, at this wave's K-eighth
  const int*   rowp = wq + (size_t)(g * 16 + c) * 8704 + (size_t)wv * 32 * 34;
  const float* xrow = x + (size_t)c * 8192 + wv * 1024 + ksub * 8;

  float4v acc = {0.f, 0.f, 0.f, 0.f};

#pragma unroll 2
  for (int j = 0; j < 32; ++j) {
    const int* bp = rowp + j * 34;          // Q8 block start (34 int32 elems)
    u2a s01 = *(const u2a*)bp;              // scale bytes (elems 0,1)
    const int* qp = bp + 2 + ksub * 8;      // this lane's 8 quants
    u2a q0 = *(const u2a*)(qp + 0);
    u2a q1 = *(const u2a*)(qp + 2);
    u2a q2 = *(const u2a*)(qp + 4);
    u2a q3 = *(const u2a*)(qp + 6);

    // fp16 scale: low bytes of elems 0,1 -> [b0, b1] -> f16 -> f32
    uint32_t sv = __builtin_amdgcn_perm(s01.y, s01.x, 0x0C0C0400u);
    const float dsc = (float)__builtin_bit_cast(_Float16, (uint16_t)sv);

    half8 bfrag;
    { union { half8 h; uint32_t u[4]; } ub;
      ub.u[0] = qpair(q0.x, q0.y);
      ub.u[1] = qpair(q1.x, q1.y);
      ub.u[2] = qpair(q2.x, q2.y);
      ub.u[3] = qpair(q3.x, q3.y);
      bfrag = ub.h; }

    // A fragment: x[row=c][k..k+8) as f16 RTZ (x is L2-resident)
    const float* xp = xrow + j * 32;
    float4v f0 = *(const f4a*)xp;
    float4v f1 = *(const f4a*)(xp + 4);
    half8 afrag;
    { union { half8 h; uint32_t u[4]; } ua;
      ua.u[0] = __builtin_bit_cast(uint32_t, __builtin_amdgcn_cvt_pkrtz(f0[0], f0[1]));
      ua.u[1] = __builtin_bit_cast(uint32_t, __builtin_amdgcn_cvt_pkrtz(f0[2], f0[3]));
      ua.u[2] = __builtin_bit_cast(uint32_t, __builtin_amdgcn_cvt_pkrtz(f1[0], f1[1]));
      ua.u[3] = __builtin_bit_cast(uint32_t, __builtin_amdgcn_cvt_pkrtz(f1[2], f1[3]));
      afrag = ua.h; }

    float4v D = __builtin_amdgcn_mfma_f32_16x16x32_f16(
        afrag, bfrag, (float4v){0.f, 0.f, 0.f, 0.f}, 0, 0, 0);
    acc[0] = fmaf(dsc, D[0], acc[0]);
    acc[1] = fmaf(dsc, D[1], acc[1]);
    acc[2] = fmaf(dsc, D[2], acc[2]);
    acc[3] = fmaf(dsc, D[3], acc[3]);
  }

  // C/D layout (m89): col = lane&15, row = (lane>>4)*4 + r
  *(f4a*)(&red[wv][c][ksub * 4]) = acc;
  __syncthreads();

  if (tid < 256) {
    const int cc = tid & 15;
    const int rr = tid >> 4;
    float s = bias[g * 16 + cc];
#pragma unroll
    for (int w = 0; w < 8; ++w) s += red[w][cc][rr];
    out[(size_t)rr * 8192 + (size_t)(g * 16 + cc)] = s;
  }
}

extern "C" void kernel_launch(void* const* d_in, const int* in_sizes, int n_in,
                              void* d_out, int out_size, void* d_ws, size_t ws_size,
                              hipStream_t stream) {
  const float* x    = (const float*)d_in[0];
  const int*   wq   = (const int*)d_in[1];
  const float* bias = (const float*)d_in[2];
  float*       out  = (float*)d_out;
  (void)in_sizes; (void)n_in; (void)d_ws; (void)ws_size; (void)out_size;
  q8lin_kernel<<<dim3(8192 / 16), dim3(512), 0, stream>>>(x, wq, bias, out);
}

// Round 5
// 56.690 us; speedup vs baseline: 1.3923x; 1.3923x over previous
//
#include <hip/hip_runtime.h>
#include <stdint.h>

// GGML Q8_0 fused dequant + GEMM:  out[16][8192] = x[16][8192] . W^T + bias
// HARNESS: quantized_weight arrives as int32, one GGML byte per element
// (zero-extended): 71,303,168 elems = 285.2 MB -> HBM-bound, ~45 us floor.
//
// R5: R4 structure, but staging uses global_load_lds WIDTH 4 (all addresses
// 4-B aligned by construction -> fixes R4's fault: width 16 needed 16-B
// aligned global sources, impossible with the 1096-B LDS row stride).
// Stride 1096 B (274 dwords, 274 % 32 == 18, gcd 2) keeps ds_read_b64 quant
// reads perfectly bank-balanced (4 accesses/bank = b64 minimum).
// Chunk = 8 Q8 blocks/row x 16 rows (4384 dwords), 72 width-4 staging slots
// (9 per wave), double-buffered, 1 barrier per chunk.

typedef _Float16 half8   __attribute__((ext_vector_type(8)));
typedef _Float16 half2v  __attribute__((ext_vector_type(2)));
typedef float    float4v __attribute__((ext_vector_type(4)));
typedef uint2    __attribute__((may_alias)) u2a;
typedef float4v  __attribute__((may_alias)) f4a;

// two zero-extended quant bytes (.b0 of lo,hi) -> packed f16 pair == exact q
__device__ __forceinline__ uint32_t qpair(uint32_t lo, uint32_t hi) {
  uint32_t r = __builtin_amdgcn_perm(hi, lo, 0x0C040C00u); // [lo.b0,0,hi.b0,0]
  r ^= 0x64806480u;                                        // f16 1152+q each
  half2v v = __builtin_bit_cast(half2v, r);
  v = v + __builtin_bit_cast(half2v, (uint32_t)0xE480E480u); // -1152,-1152
  return __builtin_bit_cast(uint32_t, v);
}

__device__ __forceinline__ void gload4(const int* g, unsigned char* l) {
  __builtin_amdgcn_global_load_lds(
      (__attribute__((address_space(1))) void*)(void*)(const_cast<int*>(g)),
      (__attribute__((address_space(3))) void*)(void*)l,
      4, 0, 0);
}

extern "C" __global__ __launch_bounds__(512, 4)
void q8lin_kernel(const float* __restrict__ x,
                  const int* __restrict__ wq,
                  const float* __restrict__ bias,
                  float* __restrict__ out)
{
  // buffer: 16 rows x 1096 B (272 data dwords + 2 pad dwords); staging spans
  // 72 slots x 256 B = 18432 B (pad lanes write clamped duplicates, unread).
  __shared__ __align__(16) unsigned char lds[2][18432];
  __shared__ __align__(16) float red[8][16][16];

  const int tid  = threadIdx.x;
  const int wv   = tid >> 6;    // wave = chunk-local Q8 block index
  const int lane = tid & 63;
  const int c    = lane & 15;   // batch row (A) and weight row / out col (B)
  const int ksub = lane >> 4;   // k-subgroup within MFMA
  const int g    = blockIdx.x;  // output cols [g*16, g*16+16)

  // staging map: slot s = wv + 8t (t=0..8); flat dword f = s*64+lane;
  // row r = f/274, in-row dword u = f-274r (clamped into [0,272) data).
  const int* gptr[9];
  unsigned   lofs[9];
#pragma unroll
  for (int t = 0; t < 9; ++t) {
    unsigned s = (unsigned)(wv + 8 * t);
    unsigned f = s * 64u + (unsigned)lane;
    unsigned r = f / 274u; if (r > 15u) r = 15u;
    unsigned u = f - r * 274u; if (u > 271u) u = 271u;
    gptr[t] = wq + (size_t)((unsigned)g * 16u + r) * 8704u + u;
    lofs[t] = s * 256u;
  }

  const float*   xrow = x + (size_t)c * 8192 + (unsigned)wv * 32u
                          + (unsigned)ksub * 8u;
  const unsigned rb   = (unsigned)c * 1096u + 136u * (unsigned)wv;
  const unsigned qb   = rb + 8u + (unsigned)ksub * 32u;

  float4v acc = {0.f, 0.f, 0.f, 0.f};

  // prologue: chunk 0
#pragma unroll
  for (int t = 0; t < 9; ++t) gload4(gptr[t], &lds[0][0] + lofs[t]);
  __syncthreads();   // compiler drains vmcnt before s_barrier

#pragma unroll 1
  for (int q = 0; q < 32; ++q) {
    const unsigned char* cur = &lds[q & 1][0];
    if (q < 31) {
      unsigned char* nxt = &lds[(q + 1) & 1][0];
      const int adv = (q + 1) * 272;
#pragma unroll
      for (int t = 0; t < 9; ++t) gload4(gptr[t] + adv, nxt + lofs[t]);
    }

    // scale: 2 int32 (bytes in .b0) at row byte 136*wv  (broadcast across ksub)
    u2a s01 = *(const u2a*)(cur + rb);
    uint32_t sv = __builtin_amdgcn_perm(s01.y, s01.x, 0x0C0C0400u);
    const float dsc = (float)__builtin_bit_cast(_Float16, (uint16_t)sv);

    // quants: 8 int32 at row byte 136*wv + 8 + ksub*32 (4x ds_read_b64,
    // bank-balanced at 4 accesses/bank thanks to the 274-dword row stride)
    u2a d0 = *(const u2a*)(cur + qb);
    u2a d1 = *(const u2a*)(cur + qb + 8);
    u2a d2 = *(const u2a*)(cur + qb + 16);
    u2a d3 = *(const u2a*)(cur + qb + 24);
    half8 bfrag;
    { union { half8 h; uint32_t u[4]; } ub;
      ub.u[0] = qpair(d0.x, d0.y);
      ub.u[1] = qpair(d1.x, d1.y);
      ub.u[2] = qpair(d2.x, d2.y);
      ub.u[3] = qpair(d3.x, d3.y);
      bfrag = ub.h; }

    // A fragment: x[c][q*256 + wv*32 + ksub*8 ..+8) as f16 RTZ (L2-resident)
    const float* xp = xrow + (size_t)q * 256;
    float4v f0 = *(const f4a*)xp;
    float4v f1 = *(const f4a*)(xp + 4);
    half8 afrag;
    { union { half8 h; uint32_t u[4]; } ua;
      ua.u[0] = __builtin_bit_cast(uint32_t, __builtin_amdgcn_cvt_pkrtz(f0[0], f0[1]));
      ua.u[1] = __builtin_bit_cast(uint32_t, __builtin_amdgcn_cvt_pkrtz(f0[2], f0[3]));
      ua.u[2] = __builtin_bit_cast(uint32_t, __builtin_amdgcn_cvt_pkrtz(f1[0], f1[1]));
      ua.u[3] = __builtin_bit_cast(uint32_t, __builtin_amdgcn_cvt_pkrtz(f1[2], f1[3]));
      afrag = ua.h; }

    float4v D = __builtin_amdgcn_mfma_f32_16x16x32_f16(
        afrag, bfrag, (float4v){0.f, 0.f, 0.f, 0.f}, 0, 0, 0);
    acc[0] = fmaf(dsc, D[0], acc[0]);
    acc[1] = fmaf(dsc, D[1], acc[1]);
    acc[2] = fmaf(dsc, D[2], acc[2]);
    acc[3] = fmaf(dsc, D[3], acc[3]);

    __syncthreads();  // next buffer complete; cur free for overwrite
  }

  // cross-wave K-reduction. C/D layout (m89): col=lane&15, row=(lane>>4)*4+r
  *(f4a*)(&red[wv][c][ksub * 4]) = acc;
  __syncthreads();

  if (tid < 256) {
    const int cc = tid & 15;
    const int rr = tid >> 4;
    float s = bias[g * 16 + cc];
#pragma unroll
    for (int w = 0; w < 8; ++w) s += red[w][cc][rr];
    out[(size_t)rr * 8192 + (size_t)(g * 16 + cc)] = s;
  }
}

extern "C" void kernel_launch(void* const* d_in, const int* in_sizes, int n_in,
                              void* d_out, int out_size, void* d_ws, size_t ws_size,
                              hipStream_t stream) {
  const float* x    = (const float*)d_in[0];
  const int*   wq   = (const int*)d_in[1];
  const float* bias = (const float*)d_in[2];
  float*       out  = (float*)d_out;
  (void)in_sizes; (void)n_in; (void)d_ws; (void)ws_size; (void)out_size;
  q8lin_kernel<<<dim3(8192 / 16), dim3(512), 0, stream>>>(x, wq, bias, out);
}